// Round 10
// baseline (213.424 us; speedup 1.0000x reference)
//
#include <hip/hip_runtime.h>
#include <math.h>

// Problem constants (from reference): S=7, NB=2, C=20
#define SS 7
#define CC 20
#define CELL_PRED 30            // C + NB*5  (120 B/cell)
#define CELL_TGT  25            // C + 1 + 4 (100 B/cell)
#define TPB 256                 // 4 waves/block, wave-PRIVATE staging: no hot-loop barriers
#define WAVES 4
#define GRID 512                // 2 blocks/CU resident -> 8 waves/CU; 512|2^32 for ticket wrap
#define NW (GRID * WAVES)       // 2048 concurrent wave-streams

// R14: R9's mixed NT/cached REGRESSED (tgt's cached swiss-cheese became the
// tail) -> revert to R7 all-NT, the best measured stream (~52us = 3.4 TB/s
// pure read). Calibration says 3.4 TB/s read-only is AT the chip's observed
// read ceiling (m13 copy 6.29 = read+write ~3.15/side; fill 6.7 is write-
// only; R8 more-outstanding null, R2 more-waves null -> per-CU line-service
// cap). Last recoverable item: fuse the final reduce via last-block-done
// ticket (saves the 2nd dispatch + gap, ~6-10us). Winner block replicates
// the old reduce kernel's arithmetic exactly (same order -> bitwise-same
// output). Ticket = __device__ global (.bss, zero at module load),
// GRID | 2^32 so graph replays stay aligned with no reset. Agent-scope
// atomics for cross-XCD visibility (G16).

#define PRED_TILE_B 7680
#define TGT_TILE_B  6400
#define TILE_FLOATS 3520        // (7680+6400)/4 floats per wave-buffer

typedef float vf4 __attribute__((ext_vector_type(4)));
typedef float vf2 __attribute__((ext_vector_type(2)));

__device__ unsigned g_ticket = 0;   // zero-initialized at module load

__device__ __forceinline__ vf4 ntload4(const float* __restrict__ p) {
    return __builtin_nontemporal_load((const vf4*)p);
}
__device__ __forceinline__ vf2 ntload2(const float* __restrict__ p) {
    return __builtin_nontemporal_load((const vf2*)p);
}
__device__ __forceinline__ float ntload1(const float* __restrict__ p) {
    return __builtin_nontemporal_load(p);
}

__device__ __forceinline__ void stage_tile_nt(const float* __restrict__ pred,
                                              const float* __restrict__ tgt,
                                              size_t t, float* lbuf, int lane)
{
    const float* gp = (const float*)((const char*)pred + t * (size_t)PRED_TILE_B);
    const float* gt = (const float*)((const char*)tgt  + t * (size_t)TGT_TILE_B);

    // ---- issue all 15 coalesced NT loads (contiguous 1KB/512B/256B spans) ----
    vf4 rp[7];
    #pragma unroll
    for (int k = 0; k < 7; ++k) rp[k] = ntload4(gp + (k * 64 + lane) * 4);  // 7x1024B
    vf2 rpt = ntload2(gp + 7168 / 4 + lane * 2);                             // 512B @7168
    vf4 rt[6];
    #pragma unroll
    for (int k = 0; k < 6; ++k) rt[k] = ntload4(gt + (k * 64 + lane) * 4);  // 6x1024B
    float rtt = ntload1(gt + 6144 / 4 + lane);                               // 256B @6144

    // ---- drain into wave-private LDS (compiler inserts counted vmcnt) ----
    vf4* lp4 = (vf4*)lbuf;
    #pragma unroll
    for (int k = 0; k < 7; ++k) lp4[k * 64 + lane] = rp[k];
    ((vf2*)lbuf)[896 + lane] = rpt;
    vf4* lt4 = (vf4*)(lbuf + PRED_TILE_B / 4);
    #pragma unroll
    for (int k = 0; k < 6; ++k) lt4[k * 64 + lane] = rt[k];
    (lbuf + PRED_TILE_B / 4)[1536 + lane] = rtt;
}

// pc = this cell's 30 pred floats (8B-aligned), tc = its 25 tgt floats.
// Works for both LDS (hot path) and global (ragged tail) pointers.
__device__ __forceinline__ float cell_loss_ptr(const float* __restrict__ pc,
                                               const float* __restrict__ tc) {
    const float EPS = 1e-6f;
    float tv[CELL_TGT];
    #pragma unroll
    for (int j = 0; j < CELL_TGT; ++j) tv[j] = tc[j];

    const float2* p2 = (const float2*)pc;
    float cls = 0.0f;
    #pragma unroll
    for (int j = 0; j < 10; ++j) {
        float2 v = p2[j];
        float d0 = v.x - tv[2 * j];
        float d1 = v.y - tv[2 * j + 1];
        cls += d0 * d0;
        cls += d1 * d1;
    }
    float b[10];
    #pragma unroll
    for (int j = 0; j < 5; ++j) {
        float2 v = p2[10 + j];
        b[2 * j] = v.x; b[2 * j + 1] = v.y;
    }
    const float* b1 = b;        // pred[20..24]
    const float* b2 = b + 5;    // pred[25..29]
    const float* tb = tv + CC;  // tgt[20..24]

    float obj = (tb[0] == 1.0f) ? 1.0f : 0.0f;

    float t_x1 = tb[0] - tb[2] * 0.5f, t_y1 = tb[1] - tb[3] * 0.5f;
    float t_x2 = tb[0] + tb[2] * 0.5f, t_y2 = tb[1] + tb[3] * 0.5f;
    float t_area = fabsf((t_x2 - t_x1) * (t_y2 - t_y1));

    float a_x1 = b1[0] - b1[2] * 0.5f, a_y1 = b1[1] - b1[3] * 0.5f;
    float a_x2 = b1[0] + b1[2] * 0.5f, a_y2 = b1[1] + b1[3] * 0.5f;
    float iw1 = fmaxf(fminf(a_x2, t_x2) - fmaxf(a_x1, t_x1), 0.0f);
    float ih1 = fmaxf(fminf(a_y2, t_y2) - fmaxf(a_y1, t_y1), 0.0f);
    float inter1 = iw1 * ih1;
    float area1 = fabsf((a_x2 - a_x1) * (a_y2 - a_y1));
    float iou1 = inter1 / (area1 + t_area - inter1 + EPS);

    float c_x1 = b2[0] - b2[2] * 0.5f, c_y1 = b2[1] - b2[3] * 0.5f;
    float c_x2 = b2[0] + b2[2] * 0.5f, c_y2 = b2[1] + b2[3] * 0.5f;
    float iw2 = fmaxf(fminf(c_x2, t_x2) - fmaxf(c_x1, t_x1), 0.0f);
    float ih2 = fmaxf(fminf(c_y2, t_y2) - fmaxf(c_y1, t_y1), 0.0f);
    float inter2 = iw2 * ih2;
    float area2 = fabsf((c_x2 - c_x1) * (c_y2 - c_y1));
    float iou2 = inter2 / (area2 + t_area - inter2 + EPS);

    bool pick1 = iou1 > iou2;
    float r0 = pick1 ? b1[0] : b2[0];
    float r1 = pick1 ? b1[1] : b2[1];
    float r2 = pick1 ? b1[2] : b2[2];
    float r3 = pick1 ? b1[3] : b2[3];
    float r4 = pick1 ? b1[4] : b2[4];

    float dx = r0 - tb[0], dy = r1 - tb[1];
    float xy = dx * dx + dy * dy;
    float dw = sqrtf(r2) - sqrtf(tb[2]);
    float dh = sqrtf(r3) - sqrtf(tb[3]);
    float wh = dw * dw + dh * dh;
    float coord = 5.0f * (xy + wh);
    float dconf = r4 - tb[4];
    float conf = dconf * dconf;

    float noobj = 0.5f * (1.0f - obj) * (b1[4] * b1[4] + b2[4] * b2[4]);
    return obj * (coord + conf + cls) + noobj;
}

__global__ __launch_bounds__(TPB) void yolo_stream(
    const float* __restrict__ pred,
    const float* __restrict__ tgt,
    float* __restrict__ partials,     // [GRID] in d_ws
    float* __restrict__ out,
    int nCells, double invN)
{
    __shared__ __align__(16) float lds[WAVES][TILE_FLOATS];  // 56,320 B
    __shared__ float s_red[WAVES];
    __shared__ double s_redd[4];
    __shared__ int s_last;
    const int tid  = threadIdx.x;
    const int lane = tid & 63;
    const int wid  = tid >> 6;
    const int gw   = blockIdx.x * WAVES + wid;   // global wave-stream id, 0..NW-1
    const int nTiles = nCells >> 6;              // 12544

    float* buf = lds[wid];                       // wave-private buffer
    float loss = 0.0f;

    // tiles gw, gw+NW, gw+2NW, ... (wavefront-coherent advance = dense DRAM window)
    const int myT = (gw < nTiles) ? ((nTiles - gw - 1) / NW + 1) : 0;
    size_t t = (size_t)gw;
    for (int i = 0; i < myT; ++i, t += NW) {
        stage_tile_nt(pred, tgt, t, buf, lane);  // 15 NT loads + ds_writes
        loss += cell_loss_ptr(buf + lane * CELL_PRED,
                              buf + (PRED_TILE_B / 4) + lane * CELL_TGT);
    }

    // ragged tail (nCells % 64 != 0; zero for N=16384): direct global path
    if (gw == 0) {
        for (int c = (nTiles << 6) + lane; c < nCells; c += 64)
            loss += cell_loss_ptr(pred + (size_t)c * CELL_PRED,
                                  tgt  + (size_t)c * CELL_TGT);
    }

    // per-wave butterfly, then 4 waves via tiny LDS
    #pragma unroll
    for (int off = 32; off > 0; off >>= 1)
        loss += __shfl_down(loss, off, 64);
    if (lane == 0) s_red[wid] = loss;
    __syncthreads();
    if (tid == 0) {
        float p = (s_red[0] + s_red[1]) + (s_red[2] + s_red[3]);
        __hip_atomic_store(&partials[blockIdx.x], p,
                           __ATOMIC_RELEASE, __HIP_MEMORY_SCOPE_AGENT);
        unsigned old = __hip_atomic_fetch_add(&g_ticket, 1u,
                           __ATOMIC_ACQ_REL, __HIP_MEMORY_SCOPE_AGENT);
        s_last = ((old & (GRID - 1)) == (GRID - 1));  // exactly one block/iter
    }
    __syncthreads();                      // block-uniform: s_last shared

    if (s_last) {
        // winner block: bitwise-identical arithmetic to the old reduce kernel
        double sum = 0.0;
        for (int i = tid; i < (GRID >> 2); i += TPB) {
            float x0 = __hip_atomic_load(&partials[4 * i + 0], __ATOMIC_RELAXED, __HIP_MEMORY_SCOPE_AGENT);
            float x1 = __hip_atomic_load(&partials[4 * i + 1], __ATOMIC_RELAXED, __HIP_MEMORY_SCOPE_AGENT);
            float x2 = __hip_atomic_load(&partials[4 * i + 2], __ATOMIC_RELAXED, __HIP_MEMORY_SCOPE_AGENT);
            float x3 = __hip_atomic_load(&partials[4 * i + 3], __ATOMIC_RELAXED, __HIP_MEMORY_SCOPE_AGENT);
            sum += (double)x0 + (double)x1 + (double)x2 + (double)x3;
        }
        #pragma unroll
        for (int off = 32; off > 0; off >>= 1)
            sum += __shfl_down(sum, off, 64);
        if ((tid & 63) == 0) s_redd[tid >> 6] = sum;
        __syncthreads();
        if (tid == 0) {
            double s = (s_redd[0] + s_redd[1]) + (s_redd[2] + s_redd[3]);
            out[0] = (float)(s * invN);
        }
    }
}

extern "C" void kernel_launch(void* const* d_in, const int* in_sizes, int n_in,
                              void* d_out, int out_size, void* d_ws, size_t ws_size,
                              hipStream_t stream) {
    const float* pred = (const float*)d_in[0];
    const float* tgt  = (const float*)d_in[1];
    float* out = (float*)d_out;
    float* partials = (float*)d_ws;

    const int N = in_sizes[0] / (SS * SS * CELL_PRED);   // 16384
    const int nCells = N * SS * SS;                      // 802816

    yolo_stream<<<GRID, TPB, 0, stream>>>(pred, tgt, partials, out,
                                          nCells, 1.0 / (double)N);
}

// Round 11
// 179.899 us; speedup vs baseline: 1.1864x; 1.1864x over previous
//
#include <hip/hip_runtime.h>
#include <math.h>

// Problem constants (from reference): S=7, NB=2, C=20
#define SS 7
#define CC 20
#define CELL_PRED 30            // C + NB*5  (120 B/cell)
#define CELL_TGT  25            // C + 1 + 4 (100 B/cell)
#define TPB 256                 // 4 waves/block, wave-PRIVATE staging: no hot-loop barriers
#define WAVES 4
#define GRID 512                // 2 blocks/CU resident -> 8 waves/CU; partials fit 4KB ws
#define NW (GRID * WAVES)       // 2048 concurrent wave-streams
#define REDUCE_BLOCK 256

// R15: STRICT REVERT to R7 (best measured: 178.6us total, stream <56.5us).
// R10 (fused reduce) regressed to 213us, but its counters show the NT
// signature GONE (FETCH 86MB + bank-conflict 150528 = exactly the cached-
// path values of R1-R3) on a DIFFERENT node (timestamp epoch changed).
// Two confounds -> revert to the known-good two-dispatch all-NT kernel.
// Decisive: ~178 total => fusion was the culprit, R7 stands as best;
// ~205-215 with stream 71-76/FETCH 86MB => node-dependent LLC state, NT
// win not portable, re-derive roofline on this node.

#define PRED_TILE_B 7680
#define TGT_TILE_B  6400
#define TILE_FLOATS 3520        // (7680+6400)/4 floats per wave-buffer

typedef float vf4 __attribute__((ext_vector_type(4)));
typedef float vf2 __attribute__((ext_vector_type(2)));

__device__ __forceinline__ vf4 ntload4(const float* __restrict__ p) {
    return __builtin_nontemporal_load((const vf4*)p);
}
__device__ __forceinline__ vf2 ntload2(const float* __restrict__ p) {
    return __builtin_nontemporal_load((const vf2*)p);
}
__device__ __forceinline__ float ntload1(const float* __restrict__ p) {
    return __builtin_nontemporal_load(p);
}

__device__ __forceinline__ void stage_tile_nt(const float* __restrict__ pred,
                                              const float* __restrict__ tgt,
                                              size_t t, float* lbuf, int lane)
{
    const float* gp = (const float*)((const char*)pred + t * (size_t)PRED_TILE_B);
    const float* gt = (const float*)((const char*)tgt  + t * (size_t)TGT_TILE_B);

    // ---- issue all 15 coalesced NT loads (contiguous 1KB/512B/256B spans) ----
    vf4 rp[7];
    #pragma unroll
    for (int k = 0; k < 7; ++k) rp[k] = ntload4(gp + (k * 64 + lane) * 4);  // 7x1024B
    vf2 rpt = ntload2(gp + 7168 / 4 + lane * 2);                             // 512B @7168
    vf4 rt[6];
    #pragma unroll
    for (int k = 0; k < 6; ++k) rt[k] = ntload4(gt + (k * 64 + lane) * 4);  // 6x1024B
    float rtt = ntload1(gt + 6144 / 4 + lane);                               // 256B @6144

    // ---- drain into wave-private LDS (compiler inserts counted vmcnt) ----
    vf4* lp4 = (vf4*)lbuf;
    #pragma unroll
    for (int k = 0; k < 7; ++k) lp4[k * 64 + lane] = rp[k];
    ((vf2*)lbuf)[896 + lane] = rpt;
    vf4* lt4 = (vf4*)(lbuf + PRED_TILE_B / 4);
    #pragma unroll
    for (int k = 0; k < 6; ++k) lt4[k * 64 + lane] = rt[k];
    (lbuf + PRED_TILE_B / 4)[1536 + lane] = rtt;
}

// pc = this cell's 30 pred floats (8B-aligned), tc = its 25 tgt floats.
// Works for both LDS (hot path) and global (ragged tail) pointers.
__device__ __forceinline__ float cell_loss_ptr(const float* __restrict__ pc,
                                               const float* __restrict__ tc) {
    const float EPS = 1e-6f;
    float tv[CELL_TGT];
    #pragma unroll
    for (int j = 0; j < CELL_TGT; ++j) tv[j] = tc[j];

    const float2* p2 = (const float2*)pc;
    float cls = 0.0f;
    #pragma unroll
    for (int j = 0; j < 10; ++j) {
        float2 v = p2[j];
        float d0 = v.x - tv[2 * j];
        float d1 = v.y - tv[2 * j + 1];
        cls += d0 * d0;
        cls += d1 * d1;
    }
    float b[10];
    #pragma unroll
    for (int j = 0; j < 5; ++j) {
        float2 v = p2[10 + j];
        b[2 * j] = v.x; b[2 * j + 1] = v.y;
    }
    const float* b1 = b;        // pred[20..24]
    const float* b2 = b + 5;    // pred[25..29]
    const float* tb = tv + CC;  // tgt[20..24]

    float obj = (tb[0] == 1.0f) ? 1.0f : 0.0f;

    float t_x1 = tb[0] - tb[2] * 0.5f, t_y1 = tb[1] - tb[3] * 0.5f;
    float t_x2 = tb[0] + tb[2] * 0.5f, t_y2 = tb[1] + tb[3] * 0.5f;
    float t_area = fabsf((t_x2 - t_x1) * (t_y2 - t_y1));

    float a_x1 = b1[0] - b1[2] * 0.5f, a_y1 = b1[1] - b1[3] * 0.5f;
    float a_x2 = b1[0] + b1[2] * 0.5f, a_y2 = b1[1] + b1[3] * 0.5f;
    float iw1 = fmaxf(fminf(a_x2, t_x2) - fmaxf(a_x1, t_x1), 0.0f);
    float ih1 = fmaxf(fminf(a_y2, t_y2) - fmaxf(a_y1, t_y1), 0.0f);
    float inter1 = iw1 * ih1;
    float area1 = fabsf((a_x2 - a_x1) * (a_y2 - a_y1));
    float iou1 = inter1 / (area1 + t_area - inter1 + EPS);

    float c_x1 = b2[0] - b2[2] * 0.5f, c_y1 = b2[1] - b2[3] * 0.5f;
    float c_x2 = b2[0] + b2[2] * 0.5f, c_y2 = b2[1] + b2[3] * 0.5f;
    float iw2 = fmaxf(fminf(c_x2, t_x2) - fmaxf(c_x1, t_x1), 0.0f);
    float ih2 = fmaxf(fminf(c_y2, t_y2) - fmaxf(c_y1, t_y1), 0.0f);
    float inter2 = iw2 * ih2;
    float area2 = fabsf((c_x2 - c_x1) * (c_y2 - c_y1));
    float iou2 = inter2 / (area2 + t_area - inter2 + EPS);

    bool pick1 = iou1 > iou2;
    float r0 = pick1 ? b1[0] : b2[0];
    float r1 = pick1 ? b1[1] : b2[1];
    float r2 = pick1 ? b1[2] : b2[2];
    float r3 = pick1 ? b1[3] : b2[3];
    float r4 = pick1 ? b1[4] : b2[4];

    float dx = r0 - tb[0], dy = r1 - tb[1];
    float xy = dx * dx + dy * dy;
    float dw = sqrtf(r2) - sqrtf(tb[2]);
    float dh = sqrtf(r3) - sqrtf(tb[3]);
    float wh = dw * dw + dh * dh;
    float coord = 5.0f * (xy + wh);
    float dconf = r4 - tb[4];
    float conf = dconf * dconf;

    float noobj = 0.5f * (1.0f - obj) * (b1[4] * b1[4] + b2[4] * b2[4]);
    return obj * (coord + conf + cls) + noobj;
}

__global__ __launch_bounds__(TPB) void yolo_stream(
    const float* __restrict__ pred,
    const float* __restrict__ tgt,
    float* __restrict__ partials,     // [GRID]
    int nCells)
{
    __shared__ __align__(16) float lds[WAVES][TILE_FLOATS];  // 56,320 B
    __shared__ float s_red[WAVES];
    const int tid  = threadIdx.x;
    const int lane = tid & 63;
    const int wid  = tid >> 6;
    const int gw   = blockIdx.x * WAVES + wid;   // global wave-stream id, 0..NW-1
    const int nTiles = nCells >> 6;              // 12544

    float* buf = lds[wid];                       // wave-private buffer
    float loss = 0.0f;

    // tiles gw, gw+NW, gw+2NW, ...
    const int myT = (gw < nTiles) ? ((nTiles - gw - 1) / NW + 1) : 0;
    size_t t = (size_t)gw;
    for (int i = 0; i < myT; ++i, t += NW) {
        stage_tile_nt(pred, tgt, t, buf, lane);  // 15 NT loads + ds_writes
        loss += cell_loss_ptr(buf + lane * CELL_PRED,
                              buf + (PRED_TILE_B / 4) + lane * CELL_TGT);
    }

    // ragged tail (nCells % 64 != 0; zero for N=16384): direct global path
    if (gw == 0) {
        for (int c = (nTiles << 6) + lane; c < nCells; c += 64)
            loss += cell_loss_ptr(pred + (size_t)c * CELL_PRED,
                                  tgt  + (size_t)c * CELL_TGT);
    }

    // per-wave butterfly, then 4 waves via tiny LDS (single barrier, post-loop)
    #pragma unroll
    for (int off = 32; off > 0; off >>= 1)
        loss += __shfl_down(loss, off, 64);
    if (lane == 0) s_red[wid] = loss;
    __syncthreads();
    if (tid == 0)
        partials[blockIdx.x] = (s_red[0] + s_red[1]) + (s_red[2] + s_red[3]);
}

__global__ __launch_bounds__(REDUCE_BLOCK) void yolo_final_reduce(
    const float* __restrict__ partials, int nPartials, double invN,
    float* __restrict__ out)
{
    __shared__ double s_red[4];
    const float4* p4 = (const float4*)partials;   // d_ws is 16-aligned
    double sum = 0.0;
    for (int i = threadIdx.x; i < (nPartials >> 2); i += REDUCE_BLOCK) {
        float4 v = p4[i];
        sum += (double)v.x + (double)v.y + (double)v.z + (double)v.w;
    }
    for (int i = ((nPartials >> 2) << 2) + threadIdx.x; i < nPartials; i += REDUCE_BLOCK)
        sum += (double)partials[i];
    #pragma unroll
    for (int off = 32; off > 0; off >>= 1)
        sum += __shfl_down(sum, off, 64);
    if ((threadIdx.x & 63) == 0) s_red[threadIdx.x >> 6] = sum;
    __syncthreads();
    if (threadIdx.x == 0) {
        double s = (s_red[0] + s_red[1]) + (s_red[2] + s_red[3]);
        out[0] = (float)(s * invN);
    }
}

extern "C" void kernel_launch(void* const* d_in, const int* in_sizes, int n_in,
                              void* d_out, int out_size, void* d_ws, size_t ws_size,
                              hipStream_t stream) {
    const float* pred = (const float*)d_in[0];
    const float* tgt  = (const float*)d_in[1];
    float* out = (float*)d_out;
    float* partials = (float*)d_ws;

    const int N = in_sizes[0] / (SS * SS * CELL_PRED);   // 16384
    const int nCells = N * SS * SS;                      // 802816

    yolo_stream<<<GRID, TPB, 0, stream>>>(pred, tgt, partials, nCells);
    yolo_final_reduce<<<1, REDUCE_BLOCK, 0, stream>>>(partials, GRID, 1.0 / (double)N, out);
}